// Round 14
// baseline (293.339 us; speedup 1.0000x reference)
//
#include <hip/hip_runtime.h>
#include <hip/hip_bf16.h>
#include <math.h>

#define PIX 36864          // 192*192
#define IMW 192
#define NWIN 4465          // 47*95
#define NWIN_W 95
#define NTASK (NWIN * 6)

typedef short bf16x8 __attribute__((ext_vector_type(8)));
typedef short bf16x4 __attribute__((ext_vector_type(4)));
typedef float floatx4 __attribute__((ext_vector_type(4)));

#if defined(__has_builtin)
#  if __has_builtin(__builtin_amdgcn_rcpf)
#    define RCP(x) __builtin_amdgcn_rcpf(x)
#  endif
#endif
#ifndef RCP
#  define RCP(x) (1.0f / (x))
#endif

// native bf16 convert (RNE; compiler can fuse adjacent pairs into v_cvt_pk_bf16_f32)
__device__ __forceinline__ unsigned short f2bf(float f) {
    __hip_bfloat16 h = __float2bfloat16(f);
    return __builtin_bit_cast(unsigned short, h);
}
__device__ __forceinline__ float bf2f(unsigned short b) {
    union { unsigned u; float f; } v; v.u = ((unsigned)b) << 16;
    return v.f;
}
// XCD-aware bijective swizzle (requires nwg % 8 == 0): groups the MT m-tiles of
// one n-slab contiguously on one XCD so its private L2 serves the shared X reads.
__device__ __forceinline__ int xcd_swz(int bid, int nwg) {
    int q = nwg >> 3;
    return (bid & 7) * q + (bid >> 3);
}

// ======================= weights->bf16 + ssum zero + pack x : ONE dispatch =======================
__device__ __forceinline__ void emit3(
    const float* __restrict__ wr, const float* __restrict__ wi,
    unsigned short* __restrict__ outr, unsigned short* __restrict__ outi,
    unsigned short* __restrict__ outni, int e)
{
    outr[e] = f2bf(wr[e]);
    unsigned short b = f2bf(wi[e]);
    outi[e]  = b;
    outni[e] = b ^ 0x8000;
}

__global__ __launch_bounds__(256) void prep_kernel(
    const float* __restrict__ qwr, const float* __restrict__ qwi,
    const float* __restrict__ pwr, const float* __restrict__ pwi,
    const float* __restrict__ w2r, const float* __restrict__ w2i,
    const float* __restrict__ xr,  const float* __restrict__ xi,
    unsigned short* __restrict__ wq, unsigned short* __restrict__ wp,
    unsigned short* __restrict__ w2, float* __restrict__ ssum,
    unsigned short* __restrict__ dr, unsigned short* __restrict__ di)
{
    int blk = blockIdx.x;
    if (blk < 108)      { emit3(qwr, qwi, wq, wq + 27648, wq + 55296, blk * 256 + threadIdx.x); return; }
    if (blk < 144)      { emit3(pwr, pwi, wp, wp + 9216,  wp + 18432, (blk - 108) * 256 + threadIdx.x); return; }
    if (blk < 288)      { emit3(w2r, w2i, w2, w2 + 36864, w2 + 73728, (blk - 144) * 256 + threadIdx.x); return; }
    if (blk == 288)     { for (int j = threadIdx.x; j < 768; j += 256) ssum[j] = 0.f; return; }
    // pack x: blocks 289..2016
    int e  = blk - 289;                 // 0..1727
    int kb = e / 144;
    int n  = (e % 144) * 256 + threadIdx.x;
    bf16x8 vr, vi;
#pragma unroll
    for (int j = 0; j < 8; ++j) {
        ((unsigned short*)&vr)[j] = f2bf(xr[(size_t)(kb * 8 + j) * PIX + n]);
        ((unsigned short*)&vi)[j] = f2bf(xi[(size_t)(kb * 8 + j) * PIX + n]);
    }
    *(bf16x8*)&dr[((size_t)kb * PIX + n) * 8] = vr;
    *(bf16x8*)&di[((size_t)kb * PIX + n) * 8] = vi;
}

// ======================= complex GEMM via MFMA (QKV: pixel-major slot store) =======================
template<int K, int MT>
__global__ __launch_bounds__(256, 2) void cgemm_mfma_kernel(
    const unsigned short* __restrict__ Wr, const unsigned short* __restrict__ Wi,
    const unsigned short* __restrict__ Wni,
    const unsigned short* __restrict__ Xr, const unsigned short* __restrict__ Xi,
    unsigned short* __restrict__ Pr, int N)
{
    const int lane = threadIdx.x & 63;
    const int wave = threadIdx.x >> 6;
    const int g = lane >> 4;
    const int r = lane & 15;
    const int wg = xcd_swz(blockIdx.x, gridDim.x);
    const int m0 = (wg % MT) * 32;
    const int n0 = (wg / MT) * 256 + wave * 64;

    floatx4 accR[2][4], accI[2][4];
#pragma unroll
    for (int t = 0; t < 2; ++t)
#pragma unroll
        for (int j = 0; j < 4; ++j) {
            accR[t][j] = (floatx4){0.f, 0.f, 0.f, 0.f};
            accI[t][j] = (floatx4){0.f, 0.f, 0.f, 0.f};
        }

    for (int kc = 0; kc < K; kc += 32) {
        bf16x8 awr[2], awi[2], awni[2];
#pragma unroll
        for (int t = 0; t < 2; ++t) {
            size_t wb = (size_t)(m0 + t * 16 + r) * K + kc + g * 8;
            awr[t]  = *(const bf16x8*)&Wr[wb];
            awi[t]  = *(const bf16x8*)&Wi[wb];
            awni[t] = *(const bf16x8*)&Wni[wb];
        }
        bf16x8 bxr[4], bxi[4];
        const size_t krow = (size_t)((kc >> 3) + g);
#pragma unroll
        for (int j = 0; j < 4; ++j) {
            size_t off = (krow * N + n0 + j * 16 + r) * 8;
            bxr[j] = *(const bf16x8*)&Xr[off];
            bxi[j] = *(const bf16x8*)&Xi[off];
        }
#pragma unroll
        for (int t = 0; t < 2; ++t)
#pragma unroll
            for (int j = 0; j < 4; ++j) {
                accR[t][j] = __builtin_amdgcn_mfma_f32_16x16x32_bf16(awr[t],  bxr[j], accR[t][j], 0, 0, 0);
                accR[t][j] = __builtin_amdgcn_mfma_f32_16x16x32_bf16(awni[t], bxi[j], accR[t][j], 0, 0, 0);
                accI[t][j] = __builtin_amdgcn_mfma_f32_16x16x32_bf16(awr[t],  bxi[j], accI[t][j], 0, 0, 0);
                accI[t][j] = __builtin_amdgcn_mfma_f32_16x16x32_bf16(awi[t],  bxr[j], accI[t][j], 0, 0, 0);
            }
    }

#pragma unroll
    for (int t = 0; t < 2; ++t) {
        int ch0 = m0 + t * 16;
        int which = ch0 / 96;
        int hh = (ch0 % 96) / 16;
#pragma unroll
        for (int j = 0; j < 4; ++j) {
            int col = n0 + j * 16 + r;
            bf16x4 pr, pi;
#pragma unroll
            for (int reg = 0; reg < 4; ++reg) {
                ((unsigned short*)&pr)[reg] = f2bf(accR[t][j][reg]);
                ((unsigned short*)&pi)[reg] = f2bf(accI[t][j][reg]);
            }
            size_t sb = (((size_t)col * 3 + which) * 6 + hh) * 32;
            *(bf16x4*)&Pr[sb + g * 4]      = pr;
            *(bf16x4*)&Pr[sb + 16 + g * 4] = pi;
        }
    }
}

// ======================= proj GEMM + FUSED combine epilogue =======================
// s1 = acc(proj, fp32) + x -> packed bf16 + BN1 stats
__global__ __launch_bounds__(256, 2) void proj_combine_kernel(
    const unsigned short* __restrict__ Wr, const unsigned short* __restrict__ Wi,
    const unsigned short* __restrict__ Wni,
    const unsigned short* __restrict__ Xr, const unsigned short* __restrict__ Xi,  // folded attn (packed)
    const float* __restrict__ xr, const float* __restrict__ xi,                    // residual x (fp32 planar)
    unsigned short* __restrict__ s1r, unsigned short* __restrict__ s1i,            // packed s1 out
    float* __restrict__ ssum1)
{
    const int K = 96, MT = 3;
    const int lane = threadIdx.x & 63;
    const int wave = threadIdx.x >> 6;
    const int g = lane >> 4;
    const int r = lane & 15;
    const int wg = xcd_swz(blockIdx.x, gridDim.x);   // 432 % 8 == 0
    const int m0 = (wg % MT) * 32;
    const int n0 = (wg / MT) * 256 + wave * 64;

    floatx4 accR[2][4], accI[2][4];
#pragma unroll
    for (int t = 0; t < 2; ++t)
#pragma unroll
        for (int j = 0; j < 4; ++j) {
            accR[t][j] = (floatx4){0.f, 0.f, 0.f, 0.f};
            accI[t][j] = (floatx4){0.f, 0.f, 0.f, 0.f};
        }

    for (int kc = 0; kc < K; kc += 32) {
        bf16x8 awr[2], awi[2], awni[2];
#pragma unroll
        for (int t = 0; t < 2; ++t) {
            size_t wb = (size_t)(m0 + t * 16 + r) * K + kc + g * 8;
            awr[t]  = *(const bf16x8*)&Wr[wb];
            awi[t]  = *(const bf16x8*)&Wi[wb];
            awni[t] = *(const bf16x8*)&Wni[wb];
        }
        bf16x8 bxr[4], bxi[4];
        const size_t krow = (size_t)((kc >> 3) + g);
#pragma unroll
        for (int j = 0; j < 4; ++j) {
            size_t off = (krow * (size_t)PIX + n0 + j * 16 + r) * 8;
            bxr[j] = *(const bf16x8*)&Xr[off];
            bxi[j] = *(const bf16x8*)&Xi[off];
        }
#pragma unroll
        for (int t = 0; t < 2; ++t)
#pragma unroll
            for (int j = 0; j < 4; ++j) {
                accR[t][j] = __builtin_amdgcn_mfma_f32_16x16x32_bf16(awr[t],  bxr[j], accR[t][j], 0, 0, 0);
                accR[t][j] = __builtin_amdgcn_mfma_f32_16x16x32_bf16(awni[t], bxi[j], accR[t][j], 0, 0, 0);
                accI[t][j] = __builtin_amdgcn_mfma_f32_16x16x32_bf16(awr[t],  bxi[j], accI[t][j], 0, 0, 0);
                accI[t][j] = __builtin_amdgcn_mfma_f32_16x16x32_bf16(awi[t],  bxr[j], accI[t][j], 0, 0, 0);
            }
    }

    // ---- fused combine epilogue: s1 = acc + x, packed store + BN1 stats ----
    float st[32];
#pragma unroll
    for (int v = 0; v < 32; ++v) st[v] = 0.f;

#pragma unroll
    for (int t = 0; t < 2; ++t) {
        size_t rowblk = (size_t)((m0 + t * 16 + g * 4) >> 3);
        int sub = (g & 1) * 4;
#pragma unroll
        for (int j = 0; j < 4; ++j) {
            int col = n0 + j * 16 + r;
            bf16x4 pr, pi;
#pragma unroll
            for (int reg = 0; reg < 4; ++reg) {
                int row = m0 + t * 16 + g * 4 + reg;
                float vr = accR[t][j][reg] + xr[(size_t)row * PIX + col];
                float vi = accI[t][j][reg] + xi[(size_t)row * PIX + col];
                ((unsigned short*)&pr)[reg] = f2bf(vr);
                ((unsigned short*)&pi)[reg] = f2bf(vi);
                int s = t * 4 + reg;
                st[s * 4 + 0] += vr; st[s * 4 + 1] += vr * vr;
                st[s * 4 + 2] += vi; st[s * 4 + 3] += vi * vi;
            }
            *(bf16x4*)&s1r[(rowblk * PIX + col) * 8 + sub] = pr;
            *(bf16x4*)&s1i[(rowblk * PIX + col) * 8 + sub] = pi;
        }
    }

    // reduce over the 16 r-lanes
#pragma unroll
    for (int v = 0; v < 32; ++v)
#pragma unroll
        for (int msk = 1; msk < 16; msk <<= 1)
            st[v] += __shfl_xor(st[v], msk, 64);
    __shared__ float red[4][4][32];
    if (r == 0)
#pragma unroll
        for (int v = 0; v < 32; ++v) red[wave][g][v] = st[v];
    __syncthreads();
    if (threadIdx.x < 128) {
        int gg = threadIdx.x >> 5;
        int v  = threadIdx.x & 31;
        float s = red[0][gg][v] + red[1][gg][v] + red[2][gg][v] + red[3][gg][v];
        int tr   = v >> 2;
        int stat = v & 3;
        int row  = m0 + (tr >> 2) * 16 + gg * 4 + (tr & 3);
        int base = (stat < 2) ? row : 96 + row;
        atomicAdd(&ssum1[base * 2 + (stat & 1)], s);
    }
}

// ======================= mlp2 GEMM + FUSED addbn epilogue =======================
__global__ __launch_bounds__(256, 2) void mlp2_addbn_kernel(
    const unsigned short* __restrict__ Wr, const unsigned short* __restrict__ Wi,
    const unsigned short* __restrict__ Wni,
    const unsigned short* __restrict__ Xr, const unsigned short* __restrict__ Xi,
    const unsigned short* __restrict__ dr, const unsigned short* __restrict__ di,  // packed s1
    const float* __restrict__ ssum1,
    const float* __restrict__ gr, const float* __restrict__ br,
    const float* __restrict__ gi, const float* __restrict__ bi,
    unsigned short* __restrict__ s2r, unsigned short* __restrict__ s2i,
    float* __restrict__ ssum2)
{
    const int K = 384, MT = 3;
    const int lane = threadIdx.x & 63;
    const int wave = threadIdx.x >> 6;
    const int g = lane >> 4;
    const int r = lane & 15;
    const int wg = xcd_swz(blockIdx.x, gridDim.x);   // 432 % 8 == 0
    const int m0 = (wg % MT) * 32;
    const int n0 = (wg / MT) * 256 + wave * 64;

    floatx4 accR[2][4], accI[2][4];
#pragma unroll
    for (int t = 0; t < 2; ++t)
#pragma unroll
        for (int j = 0; j < 4; ++j) {
            accR[t][j] = (floatx4){0.f, 0.f, 0.f, 0.f};
            accI[t][j] = (floatx4){0.f, 0.f, 0.f, 0.f};
        }

    for (int kc = 0; kc < K; kc += 32) {
        bf16x8 awr[2], awi[2], awni[2];
#pragma unroll
        for (int t = 0; t < 2; ++t) {
            size_t wb = (size_t)(m0 + t * 16 + r) * K + kc + g * 8;
            awr[t]  = *(const bf16x8*)&Wr[wb];
            awi[t]  = *(const bf16x8*)&Wi[wb];
            awni[t] = *(const bf16x8*)&Wni[wb];
        }
        bf16x8 bxr[4], bxi[4];
        const size_t krow = (size_t)((kc >> 3) + g);
#pragma unroll
        for (int j = 0; j < 4; ++j) {
            size_t off = (krow * (size_t)PIX + n0 + j * 16 + r) * 8;
            bxr[j] = *(const bf16x8*)&Xr[off];
            bxi[j] = *(const bf16x8*)&Xi[off];
        }
#pragma unroll
        for (int t = 0; t < 2; ++t)
#pragma unroll
            for (int j = 0; j < 4; ++j) {
                accR[t][j] = __builtin_amdgcn_mfma_f32_16x16x32_bf16(awr[t],  bxr[j], accR[t][j], 0, 0, 0);
                accR[t][j] = __builtin_amdgcn_mfma_f32_16x16x32_bf16(awni[t], bxi[j], accR[t][j], 0, 0, 0);
                accI[t][j] = __builtin_amdgcn_mfma_f32_16x16x32_bf16(awr[t],  bxi[j], accI[t][j], 0, 0, 0);
                accI[t][j] = __builtin_amdgcn_mfma_f32_16x16x32_bf16(awi[t],  bxr[j], accI[t][j], 0, 0, 0);
            }
    }

    // ---- fused addbn epilogue ----
    const float invn = 1.0f / (float)PIX;
    float a1r[2][4], c1r[2][4], a1i[2][4], c1i[2][4];
#pragma unroll
    for (int t = 0; t < 2; ++t)
#pragma unroll
        for (int reg = 0; reg < 4; ++reg) {
            int row = m0 + t * 16 + g * 4 + reg;
            float mr = ssum1[row * 2] * invn;
            a1r[t][reg] = gr[row] * rsqrtf(ssum1[row * 2 + 1] * invn - mr * mr + 1e-5f);
            c1r[t][reg] = br[row] - a1r[t][reg] * mr;
            float mi = ssum1[(96 + row) * 2] * invn;
            a1i[t][reg] = gi[row] * rsqrtf(ssum1[(96 + row) * 2 + 1] * invn - mi * mi + 1e-5f);
            c1i[t][reg] = bi[row] - a1i[t][reg] * mi;
        }

    float st[32];
#pragma unroll
    for (int v = 0; v < 32; ++v) st[v] = 0.f;

#pragma unroll
    for (int t = 0; t < 2; ++t) {
        size_t rowblk = (size_t)((m0 + t * 16 + g * 4) >> 3);
        int sub = (g & 1) * 4;
#pragma unroll
        for (int j = 0; j < 4; ++j) {
            int col = n0 + j * 16 + r;
            bf16x4 s1rv = *(const bf16x4*)&dr[(rowblk * PIX + col) * 8 + sub];
            bf16x4 s1iv = *(const bf16x4*)&di[(rowblk * PIX + col) * 8 + sub];
#pragma unroll
            for (int reg = 0; reg < 4; ++reg) {
                int row = m0 + t * 16 + g * 4 + reg;
                float vr = accR[t][j][reg] + a1r[t][reg] * bf2f((unsigned short)s1rv[reg]) + c1r[t][reg];
                float vi = accI[t][j][reg] + a1i[t][reg] * bf2f((unsigned short)s1iv[reg]) + c1i[t][reg];
                s2r[(size_t)row * PIX + col] = f2bf(vr);
                s2i[(size_t)row * PIX + col] = f2bf(vi);
                int s = t * 4 + reg;
                st[s * 4 + 0] += vr; st[s * 4 + 1] += vr * vr;
                st[s * 4 + 2] += vi; st[s * 4 + 3] += vi * vi;
            }
        }
    }

    // reduce over the 16 r-lanes
#pragma unroll
    for (int v = 0; v < 32; ++v)
#pragma unroll
        for (int msk = 1; msk < 16; msk <<= 1)
            st[v] += __shfl_xor(st[v], msk, 64);
    __shared__ float red[4][4][32];
    if (r == 0)
#pragma unroll
        for (int v = 0; v < 32; ++v) red[wave][g][v] = st[v];
    __syncthreads();
    if (threadIdx.x < 128) {
        int gg = threadIdx.x >> 5;
        int v  = threadIdx.x & 31;
        float s = red[0][gg][v] + red[1][gg][v] + red[2][gg][v] + red[3][gg][v];
        int tr   = v >> 2;
        int stat = v & 3;
        int row  = m0 + (tr >> 2) * 16 + gg * 4 + (tr & 3);
        int base = (stat < 2) ? row : 96 + row;
        atomicAdd(&ssum2[base * 2 + (stat & 1)], s);
    }
}

// ======================= MFMA attention (swapped QK^T -> in-register softmax) =======================
__global__ __launch_bounds__(256) void attn_mfma_kernel(
    const unsigned short* __restrict__ qkvb,
    const float* __restrict__ rel,
    unsigned short* __restrict__ wout)
{
    __shared__ unsigned vLDS[4][32 * 17];

    const int wv   = threadIdx.x >> 6;
    const int lane = threadIdx.x & 63;
    const int lr   = lane & 15;
    const int g    = lane >> 4;

    int t = blockIdx.x * 4 + wv;
    if (t >= NTASK) t = NTASK - 1;
    const int w = t / 6, h = t % 6;
    const int nh = w / NWIN_W, nw = w % NWIN_W;
    const int r0 = nh * 4, c0 = nw * 2;
    const int slot = ((nh & 1) << 1) | (nw & 1);

    unsigned* VL = vLDS[wv];

    auto slotq = [&](int p, int which) -> size_t {
        int gpix = (r0 + (p >> 2)) * IMW + c0 + (p & 3);
        return ((size_t)gpix * 18 + which * 6 + h) * 32;
    };

    {   // stage V into LDS as packed (re | im<<16)
        int m = lane & 31;
        int half = lane >> 5;
        size_t sv = slotq(m, 2);
        const bf16x8 vr = *(const bf16x8*)&qkvb[sv + half * 8];
        const bf16x8 vi = *(const bf16x8*)&qkvb[sv + 16 + half * 8];
#pragma unroll
        for (int j = 0; j < 8; ++j) {
            unsigned pk = (unsigned)(unsigned short)vr[j] |
                          ((unsigned)(unsigned short)vi[j] << 16);
            VL[m * 17 + half * 8 + j] = pk;
        }
    }

    const int hoff = (g >> 1) * 16;
    const int loff = (g & 1) * 8;
    // swapped operands: conjugate sign-flip applies to the g<2 (re-channel) slots of Q
    const unsigned smq = (g < 2) ? 0x80008000u : 0u;
    bf16x8 AkRe[2], AkIm[2], BqRe[2], BqIm[2];
#pragma unroll
    for (int tt = 0; tt < 2; ++tt) {
        size_t sq = slotq(tt * 16 + lr, 0);
        size_t sk = slotq(tt * 16 + lr, 1);
        AkRe[tt] = *(const bf16x8*)&qkvb[sk + hoff + loff];
        AkIm[tt] = *(const bf16x8*)&qkvb[sk + (16 - hoff) + loff];
        BqRe[tt] = *(const bf16x8*)&qkvb[sq + hoff + loff];
        bf16x8 tmp = BqRe[tt];
        unsigned* u = (unsigned*)&tmp;
        u[0] ^= smq; u[1] ^= smq; u[2] ^= smq; u[3] ^= smq;
        BqIm[tt] = tmp;
    }

    const floatx4 z4 = (floatx4){0.f, 0.f, 0.f, 0.f};
    // Sre[tm][tn] holds S[q = tn*16+lr][k = tm*16+g*4+reg]
    floatx4 Sre[2][2], Sim[2][2];
#pragma unroll
    for (int tm = 0; tm < 2; ++tm)
#pragma unroll
        for (int tn = 0; tn < 2; ++tn) {
            Sre[tm][tn] = __builtin_amdgcn_mfma_f32_16x16x32_bf16(AkRe[tm], BqRe[tn], z4, 0, 0, 0);
            Sim[tm][tn] = __builtin_amdgcn_mfma_f32_16x16x32_bf16(AkIm[tm], BqIm[tn], z4, 0, 0, 0);
        }

    const float* relh = rel + h * 105;
    bf16x8 pa[2][2];   // P fragments: pa[tn][kc] is this lane's PV A-operand
#pragma unroll
    for (int tn = 0; tn < 2; ++tn) {
        float re8[8], im8[8], mg8[8], rr8[8];
#pragma unroll
        for (int tm = 0; tm < 2; ++tm)
#pragma unroll
            for (int reg = 0; reg < 4; ++reg) {
                int j = tm * 4 + reg;
                // q pixel = (tn*4 + (lr>>2), lr&3); k pixel = (tm*4 + g, reg)
                int bidx = ((tn * 4 + (lr >> 2)) - (tm * 4 + g) + 7) * 7 + ((lr & 3) - reg + 3);
                float re = Sre[tm][tn][reg] * 0.25f + relh[bidx];
                float im = Sim[tm][tn][reg] * 0.25f;
                re8[j] = re; im8[j] = im;
                float m2 = fmaf(re, re, im * im);
                float rv = rsqrtf(m2 + 1e-16f);   // mag = m2*rv, 1/(mag+eps) ~= rv
                rr8[j] = rv;
                mg8[j] = m2 * rv;
            }
        float mx = mg8[0];
#pragma unroll
        for (int j = 1; j < 8; ++j) mx = fmaxf(mx, mg8[j]);
        mx = fmaxf(mx, __shfl_xor(mx, 16, 64));
        mx = fmaxf(mx, __shfl_xor(mx, 32, 64));
        float es8[8], ss = 0.f;
#pragma unroll
        for (int j = 0; j < 8; ++j) { es8[j] = __expf(mg8[j] - mx); ss += es8[j]; }
        ss += __shfl_xor(ss, 16, 64);
        ss += __shfl_xor(ss, 32, 64);
        float inv = RCP(ss);
#pragma unroll
        for (int tm = 0; tm < 2; ++tm)
#pragma unroll
            for (int reg = 0; reg < 4; ++reg) {
                int j = tm * 4 + reg;
                float f = es8[j] * inv * rr8[j];
                ((unsigned short*)&pa[tn][tm])[reg * 2]     = f2bf(re8[j] * f);
                ((unsigned short*)&pa[tn][tm])[reg * 2 + 1] = f2bf(im8[j] * f);
            }
    }
    __syncthreads();   // order V-stage LDS writes (cross-lane) before PV reads

    floatx4 Pre[2] = {z4, z4}, Pim[2] = {z4, z4};
#pragma unroll
    for (int kc = 0; kc < 2; ++kc) {
        bf16x8 Bpr, Bpi;
        unsigned* bpr = (unsigned*)&Bpr;
        unsigned* bpi = (unsigned*)&Bpi;
#pragma unroll
        for (int p = 0; p < 4; ++p) {
            unsigned pv = VL[(kc * 16 + g * 4 + p) * 17 + lr];
            bpr[p] = pv ^ 0x80000000u;
            bpi[p] = (pv >> 16) | (pv << 16);
        }
#pragma unroll
        for (int tn = 0; tn < 2; ++tn) {
            Pre[tn] = __builtin_amdgcn_mfma_f32_16x16x32_bf16(pa[tn][kc], Bpr, Pre[tn], 0, 0, 0);
            Pim[tn] = __builtin_amdgcn_mfma_f32_16x16x32_bf16(pa[tn][kc], Bpi, Pim[tn], 0, 0, 0);
        }
    }

    // epilogue: wout[gpix][slot][ch][re,im]
#pragma unroll
    for (int tn = 0; tn < 2; ++tn)
#pragma unroll
        for (int reg = 0; reg < 4; ++reg) {
            int n = tn * 16 + g * 4 + reg;
            int gpix = (r0 + (n >> 2)) * IMW + c0 + (n & 3);
            int ch = h * 16 + lr;
            unsigned pk = (unsigned)f2bf(Pre[tn][reg]) |
                          ((unsigned)f2bf(Pim[tn][reg]) << 16);
            *(unsigned*)&wout[(((size_t)gpix * 4 + slot) * 96 + ch) * 2] = pk;
        }
}

// ======================= fold (pixel-major slots) + count-div + pack for proj =======================
__global__ __launch_bounds__(256) void fold_pack_kernel(
    const unsigned short* __restrict__ wout,
    unsigned short* __restrict__ dr, unsigned short* __restrict__ di)
{
    int e = blockIdx.x * 256 + threadIdx.x;   // PIX*12
    int gpix = e / 12;
    int kb   = e % 12;
    int r = gpix / IMW, c = gpix % IMW;
    int nh0 = (r >= 7) ? ((r - 4) >> 2) : 0;
    int nh1 = min(46, r >> 2);
    int nw0 = (c >= 3) ? ((c - 2) >> 1) : 0;
    int nw1 = min(94, c >> 1);

    float accr[8] = {0,0,0,0,0,0,0,0}, acci[8] = {0,0,0,0,0,0,0,0};
    int cnt = 0;
    for (int nh = nh0; nh <= nh1; ++nh)
        for (int nw = nw0; nw <= nw1; ++nw) {
            int slot = ((nh & 1) << 1) | (nw & 1);
            const unsigned short* src = &wout[(((size_t)gpix * 4 + slot) * 96 + kb * 8) * 2];
            bf16x8 a = *(const bf16x8*)&src[0];
            bf16x8 b = *(const bf16x8*)&src[8];
#pragma unroll
            for (int j = 0; j < 4; ++j) {
                accr[j]     += bf2f((unsigned short)a[j*2]);
                acci[j]     += bf2f((unsigned short)a[j*2+1]);
                accr[4 + j] += bf2f((unsigned short)b[j*2]);
                acci[4 + j] += bf2f((unsigned short)b[j*2+1]);
            }
            ++cnt;
        }
    float invc = 1.0f / ((float)cnt + 1e-8f);
    bf16x8 pr, pi;
#pragma unroll
    for (int j = 0; j < 8; ++j) {
        ((unsigned short*)&pr)[j] = f2bf(accr[j] * invc);
        ((unsigned short*)&pi)[j] = f2bf(acci[j] * invc);
    }
    *(bf16x8*)&dr[((size_t)kb * PIX + gpix) * 8] = pr;
    *(bf16x8*)&di[((size_t)kb * PIX + gpix) * 8] = pi;
}

// ======================= build BN1-folded mlp1 weights + bias =======================
__global__ __launch_bounds__(256) void scale_w_kernel(
    const float* __restrict__ w1r, const float* __restrict__ w1i,
    const float* __restrict__ gr, const float* __restrict__ br,
    const float* __restrict__ gi, const float* __restrict__ bi,
    const float* __restrict__ ssum1,
    unsigned short* __restrict__ W0, unsigned short* __restrict__ W1,
    unsigned short* __restrict__ W2, unsigned short* __restrict__ W3,
    float* __restrict__ biasR, float* __restrict__ biasI)
{
    const float invn = 1.0f / (float)PIX;
    int blk = blockIdx.x;
    if (blk < 576) {
        int e = blk * 256 + threadIdx.x;
        int mat = e / 36864;
        int idx = e % 36864;
        int k = idx % 96;
        float mr = ssum1[k * 2] * invn;
        float a_r = gr[k] * rsqrtf(ssum1[k * 2 + 1] * invn - mr * mr + 1e-5f);
        float mi = ssum1[(96 + k) * 2] * invn;
        float a_i = gi[k] * rsqrtf(ssum1[(96 + k) * 2 + 1] * invn - mi * mi + 1e-5f);
        float wr = w1r[idx], wi = w1i[idx];
        float v = (mat == 0) ? wr * a_r : (mat == 1) ? -wi * a_i
                : (mat == 2) ? wr * a_i : wi * a_r;
        unsigned short* dst = (mat == 0) ? W0 : (mat == 1) ? W1 : (mat == 2) ? W2 : W3;
        dst[idx] = f2bf(v);
    } else {
        int o = (blk - 576) * 256 + threadIdx.x;
        if (o >= 768) return;
        int isI = o >= 384;
        int oo = o % 384;
        float acc = 0.f;
        for (int k = 0; k < 96; ++k) {
            float mr = ssum1[k * 2] * invn;
            float a_r = gr[k] * rsqrtf(ssum1[k * 2 + 1] * invn - mr * mr + 1e-5f);
            float c_r = br[k] - a_r * mr;
            float mi = ssum1[(96 + k) * 2] * invn;
            float a_i = gi[k] * rsqrtf(ssum1[(96 + k) * 2 + 1] * invn - mi * mi + 1e-5f);
            float c_i = bi[k] - a_i * mi;
            float wr = w1r[oo * 96 + k], wi = w1i[oo * 96 + k];
            acc += isI ? (wr * c_i + wi * c_r) : (wr * c_r - wi * c_i);
        }
        (isI ? biasI : biasR)[oo] = acc;
    }
}

// ======================= mlp1 (BN folded) + bias + cgelu -> packed bf16 hidden =======================
// 2 m-tiles per block (64 rows): X loads (L3-latency-bound) shared across 2x the MFMAs.
// grid 6 x 144 = 864 (%8==0 for swizzle)
__global__ __launch_bounds__(256, 2) void mlp1bn_kernel(
    const unsigned short* __restrict__ W0, const unsigned short* __restrict__ W1,
    const unsigned short* __restrict__ W2, const unsigned short* __restrict__ W3,
    const float* __restrict__ biasR, const float* __restrict__ biasI,
    const unsigned short* __restrict__ Xr, const unsigned short* __restrict__ Xi,
    unsigned short* __restrict__ Pr, unsigned short* __restrict__ Pi, int N)
{
    const int lane = threadIdx.x & 63;
    const int wave = threadIdx.x >> 6;
    const int g = lane >> 4;
    const int r = lane & 15;
    const int wg = xcd_swz(blockIdx.x, gridDim.x);   // 864 % 8 == 0
    const int m0 = (wg % 6) * 64;
    const int n0 = (wg / 6) * 256 + wave * 64;
    const int K = 96;

    floatx4 accR[4][4], accI[4][4];
#pragma unroll
    for (int t = 0; t < 4; ++t)
#pragma unroll
        for (int j = 0; j < 4; ++j) {
            accR[t][j] = (floatx4){0.f, 0.f, 0.f, 0.f};
            accI[t][j] = (floatx4){0.f, 0.f, 0.f, 0.f};
        }

    for (int kc = 0; kc < K; kc += 32) {
        bf16x8 bxr[4], bxi[4];
        const size_t krow = (size_t)((kc >> 3) + g);
#pragma unroll
        for (int j = 0; j < 4; ++j) {
            size_t off = (krow * N + n0 + j * 16 + r) * 8;
            bxr[j] = *(const bf16x8*)&Xr[off];
            bxi[j] = *(const bf16x8*)&Xi[off];
        }
#pragma unroll
        for (int t = 0; t < 4; ++t) {
            size_t wb = (size_t)(m0 + t * 16 + r) * K + kc + g * 8;
            bf16x8 a0 = *(const bf16x8*)&W0[wb];
            bf16x8 a1 = *(const bf16x8*)&W1[wb];
            bf16x8 a2 = *(const bf16x8*)&W2[wb];
            bf16x8 a3 = *(const bf16x8*)&W3[wb];
#pragma unroll
            for (int j = 0; j < 4; ++j) {
                accR[t][j] = __builtin_amdgcn_mfma_f32_16x16x32_bf16(a0, bxr[j], accR[t][j], 0, 0, 0);
                accR[t][j] = __builtin_amdgcn_mfma_f32_16x16x32_bf16(a1, bxi[j], accR[t][j], 0, 0, 0);
                accI[t][j] = __builtin_amdgcn_mfma_f32_16x16x32_bf16(a2, bxi[j], accI[t][j], 0, 0, 0);
                accI[t][j] = __builtin_amdgcn_mfma_f32_16x16x32_bf16(a3, bxr[j], accI[t][j], 0, 0, 0);
            }
        }
    }

#pragma unroll
    for (int t = 0; t < 4; ++t) {
        float bR[4], bI[4];
#pragma unroll
        for (int reg = 0; reg < 4; ++reg) {
            int row = m0 + t * 16 + g * 4 + reg;
            bR[reg] = biasR[row];
            bI[reg] = biasI[row];
        }
#pragma unroll
        for (int j = 0; j < 4; ++j) {
            int col = n0 + j * 16 + r;
            size_t rowblk = (size_t)((m0 + t * 16 + g * 4) >> 3);
            int sub = (g & 1) * 4;
            bf16x4 pr, pi;
#pragma unroll
            for (int reg = 0; reg < 4; ++reg) {
                float a = accR[t][j][reg] + bR[reg];
                float b = accI[t][j][reg] + bI[reg];
                float m2 = fmaf(a, a, b * b);
                float rv = rsqrtf(m2 + 1e-16f);
                float mag = m2 * rv;
                float f = (0.5f + 0.5f * erff(mag * 0.70710678118654752f)) * mag * rv;
                ((unsigned short*)&pr)[reg] = f2bf(a * f);
                ((unsigned short*)&pi)[reg] = f2bf(b * f);
            }
            *(bf16x4*)&Pr[(rowblk * N + col) * 8 + sub] = pr;
            *(bf16x4*)&Pi[(rowblk * N + col) * 8 + sub] = pi;
        }
    }
}

// ======================= final BN2 apply (vectorized: 8 elems/thread) =======================
__global__ __launch_bounds__(256) void bn_apply_kernel(
    const unsigned short* __restrict__ s2r, const unsigned short* __restrict__ s2i,
    const float* __restrict__ gr, const float* __restrict__ br,
    const float* __restrict__ gi, const float* __restrict__ bi,
    const float* __restrict__ ssum2,
    float* __restrict__ outr, float* __restrict__ outi)
{
    size_t base = ((size_t)blockIdx.x * 256 + threadIdx.x) * 8;
    int ch = (int)(base / PIX);
    const float invn = 1.0f / (float)PIX;
    float mr = ssum2[ch * 2] * invn;
    float isr = rsqrtf(ssum2[ch * 2 + 1] * invn - mr * mr + 1e-5f);
    float mi = ssum2[(96 + ch) * 2] * invn;
    float isi = rsqrtf(ssum2[(96 + ch) * 2 + 1] * invn - mi * mi + 1e-5f);
    float gR = gr[ch], bR = br[ch], gI = gi[ch], bI = bi[ch];

    bf16x8 vr = *(const bf16x8*)&s2r[base];
    bf16x8 vi = *(const bf16x8*)&s2i[base];
    floatx4 o0, o1, p0, p1;
#pragma unroll
    for (int j = 0; j < 4; ++j) {
        o0[j] = gR * (bf2f((unsigned short)vr[j])     - mr) * isr + bR;
        o1[j] = gR * (bf2f((unsigned short)vr[j + 4]) - mr) * isr + bR;
        p0[j] = gI * (bf2f((unsigned short)vi[j])     - mi) * isi + bI;
        p1[j] = gI * (bf2f((unsigned short)vi[j + 4]) - mi) * isi + bI;
    }
    *(floatx4*)&outr[base]     = o0;
    *(floatx4*)&outr[base + 4] = o1;
    *(floatx4*)&outi[base]     = p0;
    *(floatx4*)&outi[base + 4] = p1;
}

// ======================= launch =======================
extern "C" void kernel_launch(void* const* d_in, const int* in_sizes, int n_in,
                              void* d_out, int out_size, void* d_ws, size_t ws_size,
                              hipStream_t stream)
{
    const float* x_r     = (const float*)d_in[0];
    const float* x_i     = (const float*)d_in[1];
    const float* qkv_wr  = (const float*)d_in[2];
    const float* qkv_wi  = (const float*)d_in[3];
    const float* proj_wr = (const float*)d_in[4];
    const float* proj_wi = (const float*)d_in[5];
    const float* rel     = (const float*)d_in[6];
    const float* mlp1_wr = (const float*)d_in[7];
    const float* mlp1_wi = (const float*)d_in[8];
    const float* mlp2_wr = (const float*)d_in[9];
    const float* mlp2_wi = (const float*)d_in[10];
    const float* n1_gr   = (const float*)d_in[11];
    const float* n1_br   = (const float*)d_in[12];
    const float* n1_gi   = (const float*)d_in[13];
    const float* n1_bi   = (const float*)d_in[14];
    const float* n2_gr   = (const float*)d_in[15];
    const float* n2_br   = (const float*)d_in[16];
    const float* n2_gi   = (const float*)d_in[17];
    const float* n2_bi   = (const float*)d_in[18];

    const size_t P = PIX;
    char* base = (char*)d_ws;

    unsigned short* Dr = (unsigned short*)base;           // packed x / packed folded-attn
    unsigned short* Di = Dr + 96 * P;
    char* R = (char*)(Di + 96 * P);                       // overlay region
    unsigned short* qkvb = (unsigned short*)R;            // 576*P ushorts
    unsigned short* wout = qkvb + 576 * P;                // PIX*4*96*2 ushorts (pixel-major slots)
    unsigned short* s1r  = (unsigned short*)R;            // packed s1 (96*P each) - qkvb/wout dead by then
    unsigned short* s1i  = s1r + 96 * P;
    unsigned short* hid_r = s1i + 96 * P;                 // packed hidden re (384*P)
    unsigned short* hid_i = hid_r + 384 * P;              // packed hidden im
    unsigned short* Wb = wout + (size_t)P * 4 * 96 * 2;

    unsigned short* wq = Wb;                    // 3 x 27648
    unsigned short* wp = Wb + 82944;            // 3 x 9216
    unsigned short* w2 = Wb + 110592;           // 3 x 36864
    unsigned short* W1s = Wb + 221184;          // 4 x 36864 (BN-folded mlp1)
    float* biasR = (float*)(Wb + 368640);
    float* biasI = biasR + 384;
    float* ssum1 = biasI + 384;
    float* ssum2 = ssum1 + 384;
    unsigned short* s2r = (unsigned short*)(ssum2 + 384);
    unsigned short* s2i = s2r + 96 * P;

    float* out_r = (float*)d_out;
    float* out_i = out_r + 96 * P;

    dim3 blk(256);

    // 0. weights -> bf16 + zero ssum1+ssum2 + pack x (ONE dispatch)
    prep_kernel<<<dim3(2017), blk, 0, stream>>>(
        qkv_wr, qkv_wi, proj_wr, proj_wi, mlp2_wr, mlp2_wi, x_r, x_i,
        wq, wp, w2, ssum1, Dr, Di);
    // 1. QKV gemm -> qkvb (1296 blocks, XCD-swizzled)
    cgemm_mfma_kernel<96, 9><<<dim3(9 * 144), blk, 0, stream>>>(
        wq, wq + 27648, wq + 55296, Dr, Di, qkvb, PIX);
    // 2. attention -> wout (pixel-major slots)
    attn_mfma_kernel<<<dim3((NTASK + 3) / 4), blk, 0, stream>>>(qkvb, rel, wout);
    // 3. fold + /counts + pack for proj (overwrites Dr/Di; qkvb/wout become dead after)
    fold_pack_kernel<<<dim3(1728), blk, 0, stream>>>(wout, Dr, Di);
    // 4. proj gemm + FUSED combine -> packed s1 + BN1 stats (432 blocks, XCD-swizzled)
    proj_combine_kernel<<<dim3(3 * 144), blk, 0, stream>>>(
        wp, wp + 9216, wp + 18432, Dr, Di, x_r, x_i, s1r, s1i, ssum1);
    // 5. build BN1-folded mlp1 weights + bias
    scale_w_kernel<<<dim3(579), blk, 0, stream>>>(
        mlp1_wr, mlp1_wi, n1_gr, n1_br, n1_gi, n1_bi, ssum1,
        W1s, W1s + 36864, W1s + 73728, W1s + 110592, biasR, biasI);
    // 6. mlp1 (BN folded) + bias + cgelu -> packed hidden (864 blocks, 2 m-tiles/block, XCD-swizzled)
    mlp1bn_kernel<<<dim3(6 * 144), blk, 0, stream>>>(
        W1s, W1s + 36864, W1s + 73728, W1s + 110592, biasR, biasI,
        s1r, s1i, hid_r, hid_i, PIX);
    // 7. mlp2 gemm + FUSED addbn -> s2 bf16 planar + BN2 stats (432 blocks, XCD-swizzled)
    mlp2_addbn_kernel<<<dim3(3 * 144), blk, 0, stream>>>(
        w2, w2 + 36864, w2 + 73728, hid_r, hid_i,
        s1r, s1i, ssum1, n1_gr, n1_br, n1_gi, n1_bi, s2r, s2i, ssum2);
    // 8. BN2 apply -> out (vectorized 8 elems/thread)
    bn_apply_kernel<<<dim3(1728), blk, 0, stream>>>(s2r, s2i,
        n2_gr, n2_br, n2_gi, n2_bi, ssum2, out_r, out_i);
}

// Round 15
// 290.976 us; speedup vs baseline: 1.0081x; 1.0081x over previous
//
#include <hip/hip_runtime.h>
#include <hip/hip_bf16.h>
#include <math.h>

#define PIX 36864          // 192*192
#define IMW 192
#define NWIN 4465          // 47*95
#define NWIN_W 95
#define NTASK (NWIN * 6)

typedef short bf16x8 __attribute__((ext_vector_type(8)));
typedef short bf16x4 __attribute__((ext_vector_type(4)));
typedef float floatx4 __attribute__((ext_vector_type(4)));

#if defined(__has_builtin)
#  if __has_builtin(__builtin_amdgcn_rcpf)
#    define RCP(x) __builtin_amdgcn_rcpf(x)
#  endif
#endif
#ifndef RCP
#  define RCP(x) (1.0f / (x))
#endif

// native bf16 convert (RNE; compiler can fuse adjacent pairs into v_cvt_pk_bf16_f32)
__device__ __forceinline__ unsigned short f2bf(float f) {
    __hip_bfloat16 h = __float2bfloat16(f);
    return __builtin_bit_cast(unsigned short, h);
}
__device__ __forceinline__ float bf2f(unsigned short b) {
    union { unsigned u; float f; } v; v.u = ((unsigned)b) << 16;
    return v.f;
}
// XCD-aware bijective swizzle (requires nwg % 8 == 0): groups the MT m-tiles of
// one n-slab contiguously on one XCD so its private L2 serves the shared X reads.
__device__ __forceinline__ int xcd_swz(int bid, int nwg) {
    int q = nwg >> 3;
    return (bid & 7) * q + (bid >> 3);
}

// ======================= weights->bf16 + ssum zero + pack x : ONE dispatch =======================
__device__ __forceinline__ void emit3(
    const float* __restrict__ wr, const float* __restrict__ wi,
    unsigned short* __restrict__ outr, unsigned short* __restrict__ outi,
    unsigned short* __restrict__ outni, int e)
{
    outr[e] = f2bf(wr[e]);
    unsigned short b = f2bf(wi[e]);
    outi[e]  = b;
    outni[e] = b ^ 0x8000;
}

__global__ __launch_bounds__(256) void prep_kernel(
    const float* __restrict__ qwr, const float* __restrict__ qwi,
    const float* __restrict__ pwr, const float* __restrict__ pwi,
    const float* __restrict__ w2r, const float* __restrict__ w2i,
    const float* __restrict__ xr,  const float* __restrict__ xi,
    unsigned short* __restrict__ wq, unsigned short* __restrict__ wp,
    unsigned short* __restrict__ w2, float* __restrict__ ssum,
    unsigned short* __restrict__ dr, unsigned short* __restrict__ di)
{
    int blk = blockIdx.x;
    if (blk < 108)      { emit3(qwr, qwi, wq, wq + 27648, wq + 55296, blk * 256 + threadIdx.x); return; }
    if (blk < 144)      { emit3(pwr, pwi, wp, wp + 9216,  wp + 18432, (blk - 108) * 256 + threadIdx.x); return; }
    if (blk < 288)      { emit3(w2r, w2i, w2, w2 + 36864, w2 + 73728, (blk - 144) * 256 + threadIdx.x); return; }
    if (blk == 288)     { for (int j = threadIdx.x; j < 768; j += 256) ssum[j] = 0.f; return; }
    // pack x: blocks 289..2016
    int e  = blk - 289;                 // 0..1727
    int kb = e / 144;
    int n  = (e % 144) * 256 + threadIdx.x;
    bf16x8 vr, vi;
#pragma unroll
    for (int j = 0; j < 8; ++j) {
        ((unsigned short*)&vr)[j] = f2bf(xr[(size_t)(kb * 8 + j) * PIX + n]);
        ((unsigned short*)&vi)[j] = f2bf(xi[(size_t)(kb * 8 + j) * PIX + n]);
    }
    *(bf16x8*)&dr[((size_t)kb * PIX + n) * 8] = vr;
    *(bf16x8*)&di[((size_t)kb * PIX + n) * 8] = vi;
}

// ======================= complex GEMM via MFMA (QKV: pixel-major slot store) =======================
template<int K, int MT>
__global__ __launch_bounds__(256, 2) void cgemm_mfma_kernel(
    const unsigned short* __restrict__ Wr, const unsigned short* __restrict__ Wi,
    const unsigned short* __restrict__ Wni,
    const unsigned short* __restrict__ Xr, const unsigned short* __restrict__ Xi,
    unsigned short* __restrict__ Pr, int N)
{
    const int lane = threadIdx.x & 63;
    const int wave = threadIdx.x >> 6;
    const int g = lane >> 4;
    const int r = lane & 15;
    const int wg = xcd_swz(blockIdx.x, gridDim.x);
    const int m0 = (wg % MT) * 32;
    const int n0 = (wg / MT) * 256 + wave * 64;

    floatx4 accR[2][4], accI[2][4];
#pragma unroll
    for (int t = 0; t < 2; ++t)
#pragma unroll
        for (int j = 0; j < 4; ++j) {
            accR[t][j] = (floatx4){0.f, 0.f, 0.f, 0.f};
            accI[t][j] = (floatx4){0.f, 0.f, 0.f, 0.f};
        }

    for (int kc = 0; kc < K; kc += 32) {
        bf16x8 awr[2], awi[2], awni[2];
#pragma unroll
        for (int t = 0; t < 2; ++t) {
            size_t wb = (size_t)(m0 + t * 16 + r) * K + kc + g * 8;
            awr[t]  = *(const bf16x8*)&Wr[wb];
            awi[t]  = *(const bf16x8*)&Wi[wb];
            awni[t] = *(const bf16x8*)&Wni[wb];
        }
        bf16x8 bxr[4], bxi[4];
        const size_t krow = (size_t)((kc >> 3) + g);
#pragma unroll
        for (int j = 0; j < 4; ++j) {
            size_t off = (krow * N + n0 + j * 16 + r) * 8;
            bxr[j] = *(const bf16x8*)&Xr[off];
            bxi[j] = *(const bf16x8*)&Xi[off];
        }
#pragma unroll
        for (int t = 0; t < 2; ++t)
#pragma unroll
            for (int j = 0; j < 4; ++j) {
                accR[t][j] = __builtin_amdgcn_mfma_f32_16x16x32_bf16(awr[t],  bxr[j], accR[t][j], 0, 0, 0);
                accR[t][j] = __builtin_amdgcn_mfma_f32_16x16x32_bf16(awni[t], bxi[j], accR[t][j], 0, 0, 0);
                accI[t][j] = __builtin_amdgcn_mfma_f32_16x16x32_bf16(awr[t],  bxi[j], accI[t][j], 0, 0, 0);
                accI[t][j] = __builtin_amdgcn_mfma_f32_16x16x32_bf16(awi[t],  bxr[j], accI[t][j], 0, 0, 0);
            }
    }

#pragma unroll
    for (int t = 0; t < 2; ++t) {
        int ch0 = m0 + t * 16;
        int which = ch0 / 96;
        int hh = (ch0 % 96) / 16;
#pragma unroll
        for (int j = 0; j < 4; ++j) {
            int col = n0 + j * 16 + r;
            bf16x4 pr, pi;
#pragma unroll
            for (int reg = 0; reg < 4; ++reg) {
                ((unsigned short*)&pr)[reg] = f2bf(accR[t][j][reg]);
                ((unsigned short*)&pi)[reg] = f2bf(accI[t][j][reg]);
            }
            size_t sb = (((size_t)col * 3 + which) * 6 + hh) * 32;
            *(bf16x4*)&Pr[sb + g * 4]      = pr;
            *(bf16x4*)&Pr[sb + 16 + g * 4] = pi;
        }
    }
}

// ======================= proj GEMM + FUSED combine epilogue =======================
// s1 = acc(proj, fp32) + x -> packed bf16 + BN1 stats
__global__ __launch_bounds__(256, 2) void proj_combine_kernel(
    const unsigned short* __restrict__ Wr, const unsigned short* __restrict__ Wi,
    const unsigned short* __restrict__ Wni,
    const unsigned short* __restrict__ Xr, const unsigned short* __restrict__ Xi,  // folded attn (packed)
    const float* __restrict__ xr, const float* __restrict__ xi,                    // residual x (fp32 planar)
    unsigned short* __restrict__ s1r, unsigned short* __restrict__ s1i,            // packed s1 out
    float* __restrict__ ssum1)
{
    const int K = 96, MT = 3;
    const int lane = threadIdx.x & 63;
    const int wave = threadIdx.x >> 6;
    const int g = lane >> 4;
    const int r = lane & 15;
    const int wg = xcd_swz(blockIdx.x, gridDim.x);   // 432 % 8 == 0
    const int m0 = (wg % MT) * 32;
    const int n0 = (wg / MT) * 256 + wave * 64;

    floatx4 accR[2][4], accI[2][4];
#pragma unroll
    for (int t = 0; t < 2; ++t)
#pragma unroll
        for (int j = 0; j < 4; ++j) {
            accR[t][j] = (floatx4){0.f, 0.f, 0.f, 0.f};
            accI[t][j] = (floatx4){0.f, 0.f, 0.f, 0.f};
        }

    for (int kc = 0; kc < K; kc += 32) {
        bf16x8 awr[2], awi[2], awni[2];
#pragma unroll
        for (int t = 0; t < 2; ++t) {
            size_t wb = (size_t)(m0 + t * 16 + r) * K + kc + g * 8;
            awr[t]  = *(const bf16x8*)&Wr[wb];
            awi[t]  = *(const bf16x8*)&Wi[wb];
            awni[t] = *(const bf16x8*)&Wni[wb];
        }
        bf16x8 bxr[4], bxi[4];
        const size_t krow = (size_t)((kc >> 3) + g);
#pragma unroll
        for (int j = 0; j < 4; ++j) {
            size_t off = (krow * (size_t)PIX + n0 + j * 16 + r) * 8;
            bxr[j] = *(const bf16x8*)&Xr[off];
            bxi[j] = *(const bf16x8*)&Xi[off];
        }
#pragma unroll
        for (int t = 0; t < 2; ++t)
#pragma unroll
            for (int j = 0; j < 4; ++j) {
                accR[t][j] = __builtin_amdgcn_mfma_f32_16x16x32_bf16(awr[t],  bxr[j], accR[t][j], 0, 0, 0);
                accR[t][j] = __builtin_amdgcn_mfma_f32_16x16x32_bf16(awni[t], bxi[j], accR[t][j], 0, 0, 0);
                accI[t][j] = __builtin_amdgcn_mfma_f32_16x16x32_bf16(awr[t],  bxi[j], accI[t][j], 0, 0, 0);
                accI[t][j] = __builtin_amdgcn_mfma_f32_16x16x32_bf16(awi[t],  bxr[j], accI[t][j], 0, 0, 0);
            }
    }

    // ---- fused combine epilogue: s1 = acc + x, packed store + BN1 stats ----
    float st[32];
#pragma unroll
    for (int v = 0; v < 32; ++v) st[v] = 0.f;

#pragma unroll
    for (int t = 0; t < 2; ++t) {
        size_t rowblk = (size_t)((m0 + t * 16 + g * 4) >> 3);
        int sub = (g & 1) * 4;
#pragma unroll
        for (int j = 0; j < 4; ++j) {
            int col = n0 + j * 16 + r;
            bf16x4 pr, pi;
#pragma unroll
            for (int reg = 0; reg < 4; ++reg) {
                int row = m0 + t * 16 + g * 4 + reg;
                float vr = accR[t][j][reg] + xr[(size_t)row * PIX + col];
                float vi = accI[t][j][reg] + xi[(size_t)row * PIX + col];
                ((unsigned short*)&pr)[reg] = f2bf(vr);
                ((unsigned short*)&pi)[reg] = f2bf(vi);
                int s = t * 4 + reg;
                st[s * 4 + 0] += vr; st[s * 4 + 1] += vr * vr;
                st[s * 4 + 2] += vi; st[s * 4 + 3] += vi * vi;
            }
            *(bf16x4*)&s1r[(rowblk * PIX + col) * 8 + sub] = pr;
            *(bf16x4*)&s1i[(rowblk * PIX + col) * 8 + sub] = pi;
        }
    }

    // reduce over the 16 r-lanes
#pragma unroll
    for (int v = 0; v < 32; ++v)
#pragma unroll
        for (int msk = 1; msk < 16; msk <<= 1)
            st[v] += __shfl_xor(st[v], msk, 64);
    __shared__ float red[4][4][32];
    if (r == 0)
#pragma unroll
        for (int v = 0; v < 32; ++v) red[wave][g][v] = st[v];
    __syncthreads();
    if (threadIdx.x < 128) {
        int gg = threadIdx.x >> 5;
        int v  = threadIdx.x & 31;
        float s = red[0][gg][v] + red[1][gg][v] + red[2][gg][v] + red[3][gg][v];
        int tr   = v >> 2;
        int stat = v & 3;
        int row  = m0 + (tr >> 2) * 16 + gg * 4 + (tr & 3);
        int base = (stat < 2) ? row : 96 + row;
        atomicAdd(&ssum1[base * 2 + (stat & 1)], s);
    }
}

// ======================= mlp2 GEMM + FUSED addbn epilogue =======================
__global__ __launch_bounds__(256, 2) void mlp2_addbn_kernel(
    const unsigned short* __restrict__ Wr, const unsigned short* __restrict__ Wi,
    const unsigned short* __restrict__ Wni,
    const unsigned short* __restrict__ Xr, const unsigned short* __restrict__ Xi,
    const unsigned short* __restrict__ dr, const unsigned short* __restrict__ di,  // packed s1
    const float* __restrict__ ssum1,
    const float* __restrict__ gr, const float* __restrict__ br,
    const float* __restrict__ gi, const float* __restrict__ bi,
    unsigned short* __restrict__ s2r, unsigned short* __restrict__ s2i,
    float* __restrict__ ssum2)
{
    const int K = 384, MT = 3;
    const int lane = threadIdx.x & 63;
    const int wave = threadIdx.x >> 6;
    const int g = lane >> 4;
    const int r = lane & 15;
    const int wg = xcd_swz(blockIdx.x, gridDim.x);   // 432 % 8 == 0
    const int m0 = (wg % MT) * 32;
    const int n0 = (wg / MT) * 256 + wave * 64;

    floatx4 accR[2][4], accI[2][4];
#pragma unroll
    for (int t = 0; t < 2; ++t)
#pragma unroll
        for (int j = 0; j < 4; ++j) {
            accR[t][j] = (floatx4){0.f, 0.f, 0.f, 0.f};
            accI[t][j] = (floatx4){0.f, 0.f, 0.f, 0.f};
        }

    for (int kc = 0; kc < K; kc += 32) {
        bf16x8 awr[2], awi[2], awni[2];
#pragma unroll
        for (int t = 0; t < 2; ++t) {
            size_t wb = (size_t)(m0 + t * 16 + r) * K + kc + g * 8;
            awr[t]  = *(const bf16x8*)&Wr[wb];
            awi[t]  = *(const bf16x8*)&Wi[wb];
            awni[t] = *(const bf16x8*)&Wni[wb];
        }
        bf16x8 bxr[4], bxi[4];
        const size_t krow = (size_t)((kc >> 3) + g);
#pragma unroll
        for (int j = 0; j < 4; ++j) {
            size_t off = (krow * (size_t)PIX + n0 + j * 16 + r) * 8;
            bxr[j] = *(const bf16x8*)&Xr[off];
            bxi[j] = *(const bf16x8*)&Xi[off];
        }
#pragma unroll
        for (int t = 0; t < 2; ++t)
#pragma unroll
            for (int j = 0; j < 4; ++j) {
                accR[t][j] = __builtin_amdgcn_mfma_f32_16x16x32_bf16(awr[t],  bxr[j], accR[t][j], 0, 0, 0);
                accR[t][j] = __builtin_amdgcn_mfma_f32_16x16x32_bf16(awni[t], bxi[j], accR[t][j], 0, 0, 0);
                accI[t][j] = __builtin_amdgcn_mfma_f32_16x16x32_bf16(awr[t],  bxi[j], accI[t][j], 0, 0, 0);
                accI[t][j] = __builtin_amdgcn_mfma_f32_16x16x32_bf16(awi[t],  bxr[j], accI[t][j], 0, 0, 0);
            }
    }

    // ---- fused addbn epilogue ----
    const float invn = 1.0f / (float)PIX;
    float a1r[2][4], c1r[2][4], a1i[2][4], c1i[2][4];
#pragma unroll
    for (int t = 0; t < 2; ++t)
#pragma unroll
        for (int reg = 0; reg < 4; ++reg) {
            int row = m0 + t * 16 + g * 4 + reg;
            float mr = ssum1[row * 2] * invn;
            a1r[t][reg] = gr[row] * rsqrtf(ssum1[row * 2 + 1] * invn - mr * mr + 1e-5f);
            c1r[t][reg] = br[row] - a1r[t][reg] * mr;
            float mi = ssum1[(96 + row) * 2] * invn;
            a1i[t][reg] = gi[row] * rsqrtf(ssum1[(96 + row) * 2 + 1] * invn - mi * mi + 1e-5f);
            c1i[t][reg] = bi[row] - a1i[t][reg] * mi;
        }

    float st[32];
#pragma unroll
    for (int v = 0; v < 32; ++v) st[v] = 0.f;

#pragma unroll
    for (int t = 0; t < 2; ++t) {
        size_t rowblk = (size_t)((m0 + t * 16 + g * 4) >> 3);
        int sub = (g & 1) * 4;
#pragma unroll
        for (int j = 0; j < 4; ++j) {
            int col = n0 + j * 16 + r;
            bf16x4 s1rv = *(const bf16x4*)&dr[(rowblk * PIX + col) * 8 + sub];
            bf16x4 s1iv = *(const bf16x4*)&di[(rowblk * PIX + col) * 8 + sub];
#pragma unroll
            for (int reg = 0; reg < 4; ++reg) {
                int row = m0 + t * 16 + g * 4 + reg;
                float vr = accR[t][j][reg] + a1r[t][reg] * bf2f((unsigned short)s1rv[reg]) + c1r[t][reg];
                float vi = accI[t][j][reg] + a1i[t][reg] * bf2f((unsigned short)s1iv[reg]) + c1i[t][reg];
                s2r[(size_t)row * PIX + col] = f2bf(vr);
                s2i[(size_t)row * PIX + col] = f2bf(vi);
                int s = t * 4 + reg;
                st[s * 4 + 0] += vr; st[s * 4 + 1] += vr * vr;
                st[s * 4 + 2] += vi; st[s * 4 + 3] += vi * vi;
            }
        }
    }

    // reduce over the 16 r-lanes
#pragma unroll
    for (int v = 0; v < 32; ++v)
#pragma unroll
        for (int msk = 1; msk < 16; msk <<= 1)
            st[v] += __shfl_xor(st[v], msk, 64);
    __shared__ float red[4][4][32];
    if (r == 0)
#pragma unroll
        for (int v = 0; v < 32; ++v) red[wave][g][v] = st[v];
    __syncthreads();
    if (threadIdx.x < 128) {
        int gg = threadIdx.x >> 5;
        int v  = threadIdx.x & 31;
        float s = red[0][gg][v] + red[1][gg][v] + red[2][gg][v] + red[3][gg][v];
        int tr   = v >> 2;
        int stat = v & 3;
        int row  = m0 + (tr >> 2) * 16 + gg * 4 + (tr & 3);
        int base = (stat < 2) ? row : 96 + row;
        atomicAdd(&ssum2[base * 2 + (stat & 1)], s);
    }
}

// ======================= MFMA attention (swapped QK^T -> in-register softmax) =======================
__global__ __launch_bounds__(256) void attn_mfma_kernel(
    const unsigned short* __restrict__ qkvb,
    const float* __restrict__ rel,
    unsigned short* __restrict__ wout)
{
    __shared__ unsigned vLDS[4][32 * 17];

    const int wv   = threadIdx.x >> 6;
    const int lane = threadIdx.x & 63;
    const int lr   = lane & 15;
    const int g    = lane >> 4;

    int t = blockIdx.x * 4 + wv;
    if (t >= NTASK) t = NTASK - 1;
    const int w = t / 6, h = t % 6;
    const int nh = w / NWIN_W, nw = w % NWIN_W;
    const int r0 = nh * 4, c0 = nw * 2;
    const int slot = ((nh & 1) << 1) | (nw & 1);

    unsigned* VL = vLDS[wv];

    auto slotq = [&](int p, int which) -> size_t {
        int gpix = (r0 + (p >> 2)) * IMW + c0 + (p & 3);
        return ((size_t)gpix * 18 + which * 6 + h) * 32;
    };

    {   // stage V into LDS as packed (re | im<<16)
        int m = lane & 31;
        int half = lane >> 5;
        size_t sv = slotq(m, 2);
        const bf16x8 vr = *(const bf16x8*)&qkvb[sv + half * 8];
        const bf16x8 vi = *(const bf16x8*)&qkvb[sv + 16 + half * 8];
#pragma unroll
        for (int j = 0; j < 8; ++j) {
            unsigned pk = (unsigned)(unsigned short)vr[j] |
                          ((unsigned)(unsigned short)vi[j] << 16);
            VL[m * 17 + half * 8 + j] = pk;
        }
    }

    const int hoff = (g >> 1) * 16;
    const int loff = (g & 1) * 8;
    // swapped operands: conjugate sign-flip applies to the g<2 (re-channel) slots of Q
    const unsigned smq = (g < 2) ? 0x80008000u : 0u;
    bf16x8 AkRe[2], AkIm[2], BqRe[2], BqIm[2];
#pragma unroll
    for (int tt = 0; tt < 2; ++tt) {
        size_t sq = slotq(tt * 16 + lr, 0);
        size_t sk = slotq(tt * 16 + lr, 1);
        AkRe[tt] = *(const bf16x8*)&qkvb[sk + hoff + loff];
        AkIm[tt] = *(const bf16x8*)&qkvb[sk + (16 - hoff) + loff];
        BqRe[tt] = *(const bf16x8*)&qkvb[sq + hoff + loff];
        bf16x8 tmp = BqRe[tt];
        unsigned* u = (unsigned*)&tmp;
        u[0] ^= smq; u[1] ^= smq; u[2] ^= smq; u[3] ^= smq;
        BqIm[tt] = tmp;
    }

    const floatx4 z4 = (floatx4){0.f, 0.f, 0.f, 0.f};
    // Sre[tm][tn] holds S[q = tn*16+lr][k = tm*16+g*4+reg]
    floatx4 Sre[2][2], Sim[2][2];
#pragma unroll
    for (int tm = 0; tm < 2; ++tm)
#pragma unroll
        for (int tn = 0; tn < 2; ++tn) {
            Sre[tm][tn] = __builtin_amdgcn_mfma_f32_16x16x32_bf16(AkRe[tm], BqRe[tn], z4, 0, 0, 0);
            Sim[tm][tn] = __builtin_amdgcn_mfma_f32_16x16x32_bf16(AkIm[tm], BqIm[tn], z4, 0, 0, 0);
        }

    const float* relh = rel + h * 105;
    bf16x8 pa[2][2];   // P fragments: pa[tn][kc] is this lane's PV A-operand
#pragma unroll
    for (int tn = 0; tn < 2; ++tn) {
        float re8[8], im8[8], mg8[8], rr8[8];
#pragma unroll
        for (int tm = 0; tm < 2; ++tm)
#pragma unroll
            for (int reg = 0; reg < 4; ++reg) {
                int j = tm * 4 + reg;
                // q pixel = (tn*4 + (lr>>2), lr&3); k pixel = (tm*4 + g, reg)
                int bidx = ((tn * 4 + (lr >> 2)) - (tm * 4 + g) + 7) * 7 + ((lr & 3) - reg + 3);
                float re = Sre[tm][tn][reg] * 0.25f + relh[bidx];
                float im = Sim[tm][tn][reg] * 0.25f;
                re8[j] = re; im8[j] = im;
                float m2 = fmaf(re, re, im * im);
                float rv = rsqrtf(m2 + 1e-16f);   // mag = m2*rv, 1/(mag+eps) ~= rv
                rr8[j] = rv;
                mg8[j] = m2 * rv;
            }
        float mx = mg8[0];
#pragma unroll
        for (int j = 1; j < 8; ++j) mx = fmaxf(mx, mg8[j]);
        mx = fmaxf(mx, __shfl_xor(mx, 16, 64));
        mx = fmaxf(mx, __shfl_xor(mx, 32, 64));
        float es8[8], ss = 0.f;
#pragma unroll
        for (int j = 0; j < 8; ++j) { es8[j] = __expf(mg8[j] - mx); ss += es8[j]; }
        ss += __shfl_xor(ss, 16, 64);
        ss += __shfl_xor(ss, 32, 64);
        float inv = RCP(ss);
#pragma unroll
        for (int tm = 0; tm < 2; ++tm)
#pragma unroll
            for (int reg = 0; reg < 4; ++reg) {
                int j = tm * 4 + reg;
                float f = es8[j] * inv * rr8[j];
                ((unsigned short*)&pa[tn][tm])[reg * 2]     = f2bf(re8[j] * f);
                ((unsigned short*)&pa[tn][tm])[reg * 2 + 1] = f2bf(im8[j] * f);
            }
    }
    __syncthreads();   // order V-stage LDS writes (cross-lane) before PV reads

    floatx4 Pre[2] = {z4, z4}, Pim[2] = {z4, z4};
#pragma unroll
    for (int kc = 0; kc < 2; ++kc) {
        bf16x8 Bpr, Bpi;
        unsigned* bpr = (unsigned*)&Bpr;
        unsigned* bpi = (unsigned*)&Bpi;
#pragma unroll
        for (int p = 0; p < 4; ++p) {
            unsigned pv = VL[(kc * 16 + g * 4 + p) * 17 + lr];
            bpr[p] = pv ^ 0x80000000u;
            bpi[p] = (pv >> 16) | (pv << 16);
        }
#pragma unroll
        for (int tn = 0; tn < 2; ++tn) {
            Pre[tn] = __builtin_amdgcn_mfma_f32_16x16x32_bf16(pa[tn][kc], Bpr, Pre[tn], 0, 0, 0);
            Pim[tn] = __builtin_amdgcn_mfma_f32_16x16x32_bf16(pa[tn][kc], Bpi, Pim[tn], 0, 0, 0);
        }
    }

    // epilogue: wout[gpix][slot][ch][re,im]
#pragma unroll
    for (int tn = 0; tn < 2; ++tn)
#pragma unroll
        for (int reg = 0; reg < 4; ++reg) {
            int n = tn * 16 + g * 4 + reg;
            int gpix = (r0 + (n >> 2)) * IMW + c0 + (n & 3);
            int ch = h * 16 + lr;
            unsigned pk = (unsigned)f2bf(Pre[tn][reg]) |
                          ((unsigned)f2bf(Pim[tn][reg]) << 16);
            *(unsigned*)&wout[(((size_t)gpix * 4 + slot) * 96 + ch) * 2] = pk;
        }
}

// ======================= fold (pixel-major slots) + count-div + pack for proj =======================
__global__ __launch_bounds__(256) void fold_pack_kernel(
    const unsigned short* __restrict__ wout,
    unsigned short* __restrict__ dr, unsigned short* __restrict__ di)
{
    int e = blockIdx.x * 256 + threadIdx.x;   // PIX*12
    int gpix = e / 12;
    int kb   = e % 12;
    int r = gpix / IMW, c = gpix % IMW;
    int nh0 = (r >= 7) ? ((r - 4) >> 2) : 0;
    int nh1 = min(46, r >> 2);
    int nw0 = (c >= 3) ? ((c - 2) >> 1) : 0;
    int nw1 = min(94, c >> 1);

    float accr[8] = {0,0,0,0,0,0,0,0}, acci[8] = {0,0,0,0,0,0,0,0};
    int cnt = 0;
    for (int nh = nh0; nh <= nh1; ++nh)
        for (int nw = nw0; nw <= nw1; ++nw) {
            int slot = ((nh & 1) << 1) | (nw & 1);
            const unsigned short* src = &wout[(((size_t)gpix * 4 + slot) * 96 + kb * 8) * 2];
            bf16x8 a = *(const bf16x8*)&src[0];
            bf16x8 b = *(const bf16x8*)&src[8];
#pragma unroll
            for (int j = 0; j < 4; ++j) {
                accr[j]     += bf2f((unsigned short)a[j*2]);
                acci[j]     += bf2f((unsigned short)a[j*2+1]);
                accr[4 + j] += bf2f((unsigned short)b[j*2]);
                acci[4 + j] += bf2f((unsigned short)b[j*2+1]);
            }
            ++cnt;
        }
    float invc = 1.0f / ((float)cnt + 1e-8f);
    bf16x8 pr, pi;
#pragma unroll
    for (int j = 0; j < 8; ++j) {
        ((unsigned short*)&pr)[j] = f2bf(accr[j] * invc);
        ((unsigned short*)&pi)[j] = f2bf(acci[j] * invc);
    }
    *(bf16x8*)&dr[((size_t)kb * PIX + gpix) * 8] = pr;
    *(bf16x8*)&di[((size_t)kb * PIX + gpix) * 8] = pi;
}

// ======================= build BN1-folded mlp1 weights + bias =======================
__global__ __launch_bounds__(256) void scale_w_kernel(
    const float* __restrict__ w1r, const float* __restrict__ w1i,
    const float* __restrict__ gr, const float* __restrict__ br,
    const float* __restrict__ gi, const float* __restrict__ bi,
    const float* __restrict__ ssum1,
    unsigned short* __restrict__ W0, unsigned short* __restrict__ W1,
    unsigned short* __restrict__ W2, unsigned short* __restrict__ W3,
    float* __restrict__ biasR, float* __restrict__ biasI)
{
    const float invn = 1.0f / (float)PIX;
    int blk = blockIdx.x;
    if (blk < 576) {
        int e = blk * 256 + threadIdx.x;
        int mat = e / 36864;
        int idx = e % 36864;
        int k = idx % 96;
        float mr = ssum1[k * 2] * invn;
        float a_r = gr[k] * rsqrtf(ssum1[k * 2 + 1] * invn - mr * mr + 1e-5f);
        float mi = ssum1[(96 + k) * 2] * invn;
        float a_i = gi[k] * rsqrtf(ssum1[(96 + k) * 2 + 1] * invn - mi * mi + 1e-5f);
        float wr = w1r[idx], wi = w1i[idx];
        float v = (mat == 0) ? wr * a_r : (mat == 1) ? -wi * a_i
                : (mat == 2) ? wr * a_i : wi * a_r;
        unsigned short* dst = (mat == 0) ? W0 : (mat == 1) ? W1 : (mat == 2) ? W2 : W3;
        dst[idx] = f2bf(v);
    } else {
        int o = (blk - 576) * 256 + threadIdx.x;
        if (o >= 768) return;
        int isI = o >= 384;
        int oo = o % 384;
        float acc = 0.f;
        for (int k = 0; k < 96; ++k) {
            float mr = ssum1[k * 2] * invn;
            float a_r = gr[k] * rsqrtf(ssum1[k * 2 + 1] * invn - mr * mr + 1e-5f);
            float c_r = br[k] - a_r * mr;
            float mi = ssum1[(96 + k) * 2] * invn;
            float a_i = gi[k] * rsqrtf(ssum1[(96 + k) * 2 + 1] * invn - mi * mi + 1e-5f);
            float c_i = bi[k] - a_i * mi;
            float wr = w1r[oo * 96 + k], wi = w1i[oo * 96 + k];
            acc += isI ? (wr * c_i + wi * c_r) : (wr * c_r - wi * c_i);
        }
        (isI ? biasI : biasR)[oo] = acc;
    }
}

// ======================= mlp1 (BN folded) + bias + cgelu -> packed bf16 hidden =======================
// Tiles M=64 x N=128: X shared across 4 m-subtiles (round-14 win) AND grid back to
// 1728 blocks (6.75/CU) with acc=64 VGPR -> ~2x resident waves for latency hiding.
__global__ __launch_bounds__(256, 2) void mlp1bn_kernel(
    const unsigned short* __restrict__ W0, const unsigned short* __restrict__ W1,
    const unsigned short* __restrict__ W2, const unsigned short* __restrict__ W3,
    const float* __restrict__ biasR, const float* __restrict__ biasI,
    const unsigned short* __restrict__ Xr, const unsigned short* __restrict__ Xi,
    unsigned short* __restrict__ Pr, unsigned short* __restrict__ Pi, int N)
{
    const int lane = threadIdx.x & 63;
    const int wave = threadIdx.x >> 6;
    const int g = lane >> 4;
    const int r = lane & 15;
    const int wg = xcd_swz(blockIdx.x, gridDim.x);   // 1728 % 8 == 0
    const int m0 = (wg % 6) * 64;
    const int n0 = (wg / 6) * 128 + wave * 32;
    const int K = 96;

    floatx4 accR[4][2], accI[4][2];
#pragma unroll
    for (int t = 0; t < 4; ++t)
#pragma unroll
        for (int j = 0; j < 2; ++j) {
            accR[t][j] = (floatx4){0.f, 0.f, 0.f, 0.f};
            accI[t][j] = (floatx4){0.f, 0.f, 0.f, 0.f};
        }

    for (int kc = 0; kc < K; kc += 32) {
        bf16x8 bxr[2], bxi[2];
        const size_t krow = (size_t)((kc >> 3) + g);
#pragma unroll
        for (int j = 0; j < 2; ++j) {
            size_t off = (krow * N + n0 + j * 16 + r) * 8;
            bxr[j] = *(const bf16x8*)&Xr[off];
            bxi[j] = *(const bf16x8*)&Xi[off];
        }
#pragma unroll
        for (int t = 0; t < 4; ++t) {
            size_t wb = (size_t)(m0 + t * 16 + r) * K + kc + g * 8;
            bf16x8 a0 = *(const bf16x8*)&W0[wb];
            bf16x8 a1 = *(const bf16x8*)&W1[wb];
            bf16x8 a2 = *(const bf16x8*)&W2[wb];
            bf16x8 a3 = *(const bf16x8*)&W3[wb];
#pragma unroll
            for (int j = 0; j < 2; ++j) {
                accR[t][j] = __builtin_amdgcn_mfma_f32_16x16x32_bf16(a0, bxr[j], accR[t][j], 0, 0, 0);
                accR[t][j] = __builtin_amdgcn_mfma_f32_16x16x32_bf16(a1, bxi[j], accR[t][j], 0, 0, 0);
                accI[t][j] = __builtin_amdgcn_mfma_f32_16x16x32_bf16(a2, bxi[j], accI[t][j], 0, 0, 0);
                accI[t][j] = __builtin_amdgcn_mfma_f32_16x16x32_bf16(a3, bxr[j], accI[t][j], 0, 0, 0);
            }
        }
    }

#pragma unroll
    for (int t = 0; t < 4; ++t) {
        float bR[4], bI[4];
#pragma unroll
        for (int reg = 0; reg < 4; ++reg) {
            int row = m0 + t * 16 + g * 4 + reg;
            bR[reg] = biasR[row];
            bI[reg] = biasI[row];
        }
#pragma unroll
        for (int j = 0; j < 2; ++j) {
            int col = n0 + j * 16 + r;
            size_t rowblk = (size_t)((m0 + t * 16 + g * 4) >> 3);
            int sub = (g & 1) * 4;
            bf16x4 pr, pi;
#pragma unroll
            for (int reg = 0; reg < 4; ++reg) {
                float a = accR[t][j][reg] + bR[reg];
                float b = accI[t][j][reg] + bI[reg];
                float m2 = fmaf(a, a, b * b);
                float rv = rsqrtf(m2 + 1e-16f);
                float mag = m2 * rv;
                float f = (0.5f + 0.5f * erff(mag * 0.70710678118654752f)) * mag * rv;
                ((unsigned short*)&pr)[reg] = f2bf(a * f);
                ((unsigned short*)&pi)[reg] = f2bf(b * f);
            }
            *(bf16x4*)&Pr[(rowblk * N + col) * 8 + sub] = pr;
            *(bf16x4*)&Pi[(rowblk * N + col) * 8 + sub] = pi;
        }
    }
}

// ======================= final BN2 apply (vectorized: 8 elems/thread) =======================
__global__ __launch_bounds__(256) void bn_apply_kernel(
    const unsigned short* __restrict__ s2r, const unsigned short* __restrict__ s2i,
    const float* __restrict__ gr, const float* __restrict__ br,
    const float* __restrict__ gi, const float* __restrict__ bi,
    const float* __restrict__ ssum2,
    float* __restrict__ outr, float* __restrict__ outi)
{
    size_t base = ((size_t)blockIdx.x * 256 + threadIdx.x) * 8;
    int ch = (int)(base / PIX);
    const float invn = 1.0f / (float)PIX;
    float mr = ssum2[ch * 2] * invn;
    float isr = rsqrtf(ssum2[ch * 2 + 1] * invn - mr * mr + 1e-5f);
    float mi = ssum2[(96 + ch) * 2] * invn;
    float isi = rsqrtf(ssum2[(96 + ch) * 2 + 1] * invn - mi * mi + 1e-5f);
    float gR = gr[ch], bR = br[ch], gI = gi[ch], bI = bi[ch];

    bf16x8 vr = *(const bf16x8*)&s2r[base];
    bf16x8 vi = *(const bf16x8*)&s2i[base];
    floatx4 o0, o1, p0, p1;
#pragma unroll
    for (int j = 0; j < 4; ++j) {
        o0[j] = gR * (bf2f((unsigned short)vr[j])     - mr) * isr + bR;
        o1[j] = gR * (bf2f((unsigned short)vr[j + 4]) - mr) * isr + bR;
        p0[j] = gI * (bf2f((unsigned short)vi[j])     - mi) * isi + bI;
        p1[j] = gI * (bf2f((unsigned short)vi[j + 4]) - mi) * isi + bI;
    }
    *(floatx4*)&outr[base]     = o0;
    *(floatx4*)&outr[base + 4] = o1;
    *(floatx4*)&outi[base]     = p0;
    *(floatx4*)&outi[base + 4] = p1;
}

// ======================= launch =======================
extern "C" void kernel_launch(void* const* d_in, const int* in_sizes, int n_in,
                              void* d_out, int out_size, void* d_ws, size_t ws_size,
                              hipStream_t stream)
{
    const float* x_r     = (const float*)d_in[0];
    const float* x_i     = (const float*)d_in[1];
    const float* qkv_wr  = (const float*)d_in[2];
    const float* qkv_wi  = (const float*)d_in[3];
    const float* proj_wr = (const float*)d_in[4];
    const float* proj_wi = (const float*)d_in[5];
    const float* rel     = (const float*)d_in[6];
    const float* mlp1_wr = (const float*)d_in[7];
    const float* mlp1_wi = (const float*)d_in[8];
    const float* mlp2_wr = (const float*)d_in[9];
    const float* mlp2_wi = (const float*)d_in[10];
    const float* n1_gr   = (const float*)d_in[11];
    const float* n1_br   = (const float*)d_in[12];
    const float* n1_gi   = (const float*)d_in[13];
    const float* n1_bi   = (const float*)d_in[14];
    const float* n2_gr   = (const float*)d_in[15];
    const float* n2_br   = (const float*)d_in[16];
    const float* n2_gi   = (const float*)d_in[17];
    const float* n2_bi   = (const float*)d_in[18];

    const size_t P = PIX;
    char* base = (char*)d_ws;

    unsigned short* Dr = (unsigned short*)base;           // packed x / packed folded-attn
    unsigned short* Di = Dr + 96 * P;
    char* R = (char*)(Di + 96 * P);                       // overlay region
    unsigned short* qkvb = (unsigned short*)R;            // 576*P ushorts
    unsigned short* wout = qkvb + 576 * P;                // PIX*4*96*2 ushorts (pixel-major slots)
    unsigned short* s1r  = (unsigned short*)R;            // packed s1 (96*P each) - qkvb/wout dead by then
    unsigned short* s1i  = s1r + 96 * P;
    unsigned short* hid_r = s1i + 96 * P;                 // packed hidden re (384*P)
    unsigned short* hid_i = hid_r + 384 * P;              // packed hidden im
    unsigned short* Wb = wout + (size_t)P * 4 * 96 * 2;

    unsigned short* wq = Wb;                    // 3 x 27648
    unsigned short* wp = Wb + 82944;            // 3 x 9216
    unsigned short* w2 = Wb + 110592;           // 3 x 36864
    unsigned short* W1s = Wb + 221184;          // 4 x 36864 (BN-folded mlp1)
    float* biasR = (float*)(Wb + 368640);
    float* biasI = biasR + 384;
    float* ssum1 = biasI + 384;
    float* ssum2 = ssum1 + 384;
    unsigned short* s2r = (unsigned short*)(ssum2 + 384);
    unsigned short* s2i = s2r + 96 * P;

    float* out_r = (float*)d_out;
    float* out_i = out_r + 96 * P;

    dim3 blk(256);

    // 0. weights -> bf16 + zero ssum1+ssum2 + pack x (ONE dispatch)
    prep_kernel<<<dim3(2017), blk, 0, stream>>>(
        qkv_wr, qkv_wi, proj_wr, proj_wi, mlp2_wr, mlp2_wi, x_r, x_i,
        wq, wp, w2, ssum1, Dr, Di);
    // 1. QKV gemm -> qkvb (1296 blocks, XCD-swizzled)
    cgemm_mfma_kernel<96, 9><<<dim3(9 * 144), blk, 0, stream>>>(
        wq, wq + 27648, wq + 55296, Dr, Di, qkvb, PIX);
    // 2. attention -> wout (pixel-major slots)
    attn_mfma_kernel<<<dim3((NTASK + 3) / 4), blk, 0, stream>>>(qkvb, rel, wout);
    // 3. fold + /counts + pack for proj (overwrites Dr/Di; qkvb/wout become dead after)
    fold_pack_kernel<<<dim3(1728), blk, 0, stream>>>(wout, Dr, Di);
    // 4. proj gemm + FUSED combine -> packed s1 + BN1 stats (432 blocks, XCD-swizzled)
    proj_combine_kernel<<<dim3(3 * 144), blk, 0, stream>>>(
        wp, wp + 9216, wp + 18432, Dr, Di, x_r, x_i, s1r, s1i, ssum1);
    // 5. build BN1-folded mlp1 weights + bias
    scale_w_kernel<<<dim3(579), blk, 0, stream>>>(
        mlp1_wr, mlp1_wi, n1_gr, n1_br, n1_gi, n1_bi, ssum1,
        W1s, W1s + 36864, W1s + 73728, W1s + 110592, biasR, biasI);
    // 6. mlp1 (BN folded) + bias + cgelu -> packed hidden
    //    (M=64 x N=128, grid 6*288=1728: X-sharing + restored TLP, XCD-swizzled)
    mlp1bn_kernel<<<dim3(6 * 288), blk, 0, stream>>>(
        W1s, W1s + 36864, W1s + 73728, W1s + 110592, biasR, biasI,
        s1r, s1i, hid_r, hid_i, PIX);
    // 7. mlp2 gemm + FUSED addbn -> s2 bf16 planar + BN2 stats (432 blocks, XCD-swizzled)
    mlp2_addbn_kernel<<<dim3(3 * 144), blk, 0, stream>>>(
        w2, w2 + 36864, w2 + 73728, hid_r, hid_i,
        s1r, s1i, ssum1, n1_gr, n1_br, n1_gi, n1_bi, s2r, s2i, ssum2);
    // 8. BN2 apply -> out (vectorized 8 elems/thread)
    bn_apply_kernel<<<dim3(1728), blk, 0, stream>>>(s2r, s2i,
        n2_gr, n2_br, n2_gi, n2_bi, ssum2, out_r, out_i);
}